// Round 1
// baseline (31536.609 us; speedup 1.0000x reference)
//
#include <hip/hip_runtime.h>
#include <math.h>

#define HDIM   512
#define GDIM   2048      // 4*H
#define BATCH  1024
#define TSTEPS 100
#define INDIM  4
#define BM     32        // batch rows per block
#define BNHL   32        // hidden cols per block (=> 128 gate cols)
#define KT     32        // K chunk
#define XPITCH 36        // padded row pitch for transposed x tile (floats)

// ---- reorder W [4H, K] (rows j = g*512+hl) -> Wt [K, 4H] with col c = hl*4+g ----
__global__ void reorder_w(const float* __restrict__ W, float* __restrict__ Wt, int K) {
    int idx = blockIdx.x * 256 + threadIdx.x;
    if (idx >= GDIM * K) return;
    int c = idx % GDIM;
    int k = idx / GDIM;
    Wt[idx] = W[((size_t)((c & 3) * HDIM + (c >> 2))) * K + k];
}

__global__ void reorder_b(const float* __restrict__ b, float* __restrict__ bt) {
    int c = blockIdx.x * 256 + threadIdx.x;
    if (c < GDIM) bt[c] = b[(c & 3) * HDIM + (c >> 2)];
}

// ---- load one K-chunk (global -> regs) ----
__device__ __forceinline__ void load_chunk(int ci, int nc1,
        const float* x1, int ldx1, int K1, const float* W1t,
        const float* x2, const float* W2t,
        int tid, int tx, int rg, int bm0, int hl0,
        float4 (&wreg)[4], float4& xreg, int& kta)
{
    const float* xs; const float* Wt; int k0, ld, Ks;
    if (ci < nc1) { xs = x1; Wt = W1t; k0 = ci * KT;          ld = ldx1; Ks = K1;   }
    else          { xs = x2; Wt = W2t; k0 = (ci - nc1) * KT;  ld = HDIM; Ks = HDIM; }
    kta = Ks - k0; if (kta > KT) kta = KT;
    const float* wbase = Wt + (size_t)k0 * GDIM + hl0 * 4;
    if (kta == KT) {
        #pragma unroll
        for (int i = 0; i < 4; ++i)
            wreg[i] = *(const float4*)(wbase + (size_t)(rg + 8 * i) * GDIM + tx * 4);
        xreg = *(const float4*)(xs + (size_t)(bm0 + tx) * ld + k0 + rg * 4);
    } else {                       // kta == 4 (tiny input dim)
        if (tid < kta * 32)
            wreg[0] = *(const float4*)(wbase + (size_t)rg * GDIM + tx * 4);
        if (tid < 32)
            xreg = *(const float4*)(xs + (size_t)(bm0 + tx) * ld + k0);
    }
}

// ---- write one K-chunk (regs -> LDS) ----
__device__ __forceinline__ void write_chunk(float* sW, float* sX,
        int tid, int tx, int rg, const float4 (&wreg)[4], const float4& xreg, int kta)
{
    if (kta == KT) {
        #pragma unroll
        for (int i = 0; i < 4; ++i)
            *(float4*)(sW + (rg + 8 * i) * 128 + tx * 4) = wreg[i];
        sX[(rg * 4 + 0) * XPITCH + tx] = xreg.x;
        sX[(rg * 4 + 1) * XPITCH + tx] = xreg.y;
        sX[(rg * 4 + 2) * XPITCH + tx] = xreg.z;
        sX[(rg * 4 + 3) * XPITCH + tx] = xreg.w;
    } else {
        if (tid < kta * 32)
            *(float4*)(sW + rg * 128 + tx * 4) = wreg[0];
        if (tid < 32) {
            sX[0 * XPITCH + tid] = xreg.x;
            sX[1 * XPITCH + tid] = xreg.y;
            sX[2 * XPITCH + tid] = xreg.z;
            sX[3 * XPITCH + tid] = xreg.w;
        }
    }
}

// Fused: gates = x1@W1.T + x2@W2.T + b ; LSTM cell update -> h_out, c_out
// Gate columns permuted as c = hl*4 + g so each thread owns i,f,g,o of one col.
__launch_bounds__(256, 2)
__global__ void lstm_step(const float* __restrict__ x1, int ldx1, int K1,
                          const float* __restrict__ W1t,
                          const float* __restrict__ x2,
                          const float* __restrict__ W2t,
                          const float* __restrict__ bt,
                          const float* c_in, float* __restrict__ h_out, float* c_out)
{
    __shared__ __align__(16) float sW[KT * 4 * BNHL];  // [kk][128 gate cols]
    __shared__ __align__(16) float sX[KT * XPITCH];    // [kk][32 rows] (pad 36)

    const int tid = threadIdx.x;
    const int tx  = tid & 31;        // hidden col within block
    const int rg  = tid >> 5;        // row group (4 rows each)
    const int bm0 = blockIdx.x * BM;
    const int hl0 = blockIdx.y * BNHL;

    float acc[4][4] = {};            // [row][gate]
    float4 wreg[4]; float4 xreg;

    const int nc1 = (K1 + KT - 1) / KT;
    const int nch = nc1 + HDIM / KT;

    int kta;
    load_chunk(0, nc1, x1, ldx1, K1, W1t, x2, W2t, tid, tx, rg, bm0, hl0, wreg, xreg, kta);

    for (int ci = 0; ci < nch; ++ci) {
        __syncthreads();             // previous compute done reading LDS
        write_chunk(sW, sX, tid, tx, rg, wreg, xreg, kta);
        __syncthreads();
        const int cur = kta;
        if (ci + 1 < nch)            // prefetch next chunk; latency hides under FMAs
            load_chunk(ci + 1, nc1, x1, ldx1, K1, W1t, x2, W2t, tid, tx, rg, bm0, hl0, wreg, xreg, kta);
        #pragma unroll 4
        for (int kk = 0; kk < cur; ++kk) {
            float4 wv = *(const float4*)(sW + kk * 128 + tx * 4);     // i,f,g,o of col tx
            float4 xv = *(const float4*)(sX + kk * XPITCH + rg * 4);  // 4 batch rows
            acc[0][0] = fmaf(xv.x, wv.x, acc[0][0]);
            acc[0][1] = fmaf(xv.x, wv.y, acc[0][1]);
            acc[0][2] = fmaf(xv.x, wv.z, acc[0][2]);
            acc[0][3] = fmaf(xv.x, wv.w, acc[0][3]);
            acc[1][0] = fmaf(xv.y, wv.x, acc[1][0]);
            acc[1][1] = fmaf(xv.y, wv.y, acc[1][1]);
            acc[1][2] = fmaf(xv.y, wv.z, acc[1][2]);
            acc[1][3] = fmaf(xv.y, wv.w, acc[1][3]);
            acc[2][0] = fmaf(xv.z, wv.x, acc[2][0]);
            acc[2][1] = fmaf(xv.z, wv.y, acc[2][1]);
            acc[2][2] = fmaf(xv.z, wv.z, acc[2][2]);
            acc[2][3] = fmaf(xv.z, wv.w, acc[2][3]);
            acc[3][0] = fmaf(xv.w, wv.x, acc[3][0]);
            acc[3][1] = fmaf(xv.w, wv.y, acc[3][1]);
            acc[3][2] = fmaf(xv.w, wv.z, acc[3][2]);
            acc[3][3] = fmaf(xv.w, wv.w, acc[3][3]);
        }
    }

    // ---- cell update, all in registers ----
    const float4 bv = *(const float4*)(bt + (hl0 + tx) * 4);
    const int col = hl0 + tx;
    #pragma unroll
    for (int r = 0; r < 4; ++r) {
        const int row = bm0 + rg * 4 + r;
        const size_t o = (size_t)row * HDIM + col;
        float iv = acc[r][0] + bv.x;
        float fv = acc[r][1] + bv.y;
        float gv = acc[r][2] + bv.z;
        float ov = acc[r][3] + bv.w;
        float si = 1.0f / (1.0f + expf(-iv));
        float sf = 1.0f / (1.0f + expf(-fv));
        float so = 1.0f / (1.0f + expf(-ov));
        float cn = sf * c_in[o] + si * tanhf(gv);
        float hn = so * tanhf(cn);
        c_out[o] = cn;
        h_out[o] = hn;
    }
}

// pred = h1 @ Wp.T + bp  (written to out[b][t][:]), then softmax -> xfb feedback
__global__ void pred_softmax(const float* __restrict__ h1, const float* __restrict__ Wp,
                             const float* __restrict__ bp, float* __restrict__ outp,
                             float* __restrict__ xfb)
{
    const int tid = threadIdx.x;
    const int b = blockIdx.x * 16 + (tid >> 4);
    const int l = tid & 15;
    const float* hr = h1 + (size_t)b * HDIM;
    float a0 = 0.f, a1 = 0.f, a2 = 0.f, a3 = 0.f;
    #pragma unroll
    for (int j = 0; j < 8; ++j) {
        int k = j * 64 + l * 4;
        float4 hv = *(const float4*)(hr + k);
        float4 w0 = *(const float4*)(Wp + 0 * HDIM + k);
        float4 w1 = *(const float4*)(Wp + 1 * HDIM + k);
        float4 w2 = *(const float4*)(Wp + 2 * HDIM + k);
        float4 w3 = *(const float4*)(Wp + 3 * HDIM + k);
        a0 += hv.x*w0.x + hv.y*w0.y + hv.z*w0.z + hv.w*w0.w;
        a1 += hv.x*w1.x + hv.y*w1.y + hv.z*w1.z + hv.w*w1.w;
        a2 += hv.x*w2.x + hv.y*w2.y + hv.z*w2.z + hv.w*w2.w;
        a3 += hv.x*w3.x + hv.y*w3.y + hv.z*w3.z + hv.w*w3.w;
    }
    #pragma unroll
    for (int off = 8; off > 0; off >>= 1) {
        a0 += __shfl_xor(a0, off, 16);
        a1 += __shfl_xor(a1, off, 16);
        a2 += __shfl_xor(a2, off, 16);
        a3 += __shfl_xor(a3, off, 16);
    }
    if (l == 0) {
        const float4 bv = *(const float4*)bp;
        float v0 = a0 + bv.x, v1 = a1 + bv.y, v2 = a2 + bv.z, v3 = a3 + bv.w;
        float* op = outp + (size_t)b * (TSTEPS * INDIM);
        op[0] = v0; op[1] = v1; op[2] = v2; op[3] = v3;
        float m = fmaxf(fmaxf(v0, v1), fmaxf(v2, v3));
        float e0 = expf(v0 - m), e1 = expf(v1 - m), e2 = expf(v2 - m), e3 = expf(v3 - m);
        float inv = 1.0f / (e0 + e1 + e2 + e3);
        float* xp = xfb + b * 4;
        xp[0] = e0 * inv; xp[1] = e1 * inv; xp[2] = e2 * inv; xp[3] = e3 * inv;
    }
}

extern "C" void kernel_launch(void* const* d_in, const int* in_sizes, int n_in,
                              void* d_out, int out_size, void* d_ws, size_t ws_size,
                              hipStream_t stream)
{
    const float* X     = (const float*)d_in[0];
    const float* eWih0 = (const float*)d_in[2];
    const float* eWhh0 = (const float*)d_in[3];
    const float* eb0   = (const float*)d_in[4];
    const float* eWih1 = (const float*)d_in[5];
    const float* eWhh1 = (const float*)d_in[6];
    const float* eb1   = (const float*)d_in[7];
    const float* dWih0 = (const float*)d_in[8];
    const float* dWhh0 = (const float*)d_in[9];
    const float* db0   = (const float*)d_in[10];
    const float* dWih1 = (const float*)d_in[11];
    const float* dWhh1 = (const float*)d_in[12];
    const float* db1   = (const float*)d_in[13];
    const float* Wp    = (const float*)d_in[14];
    const float* bp    = (const float*)d_in[15];
    float* out = (float*)d_out;
    float* ws  = (float*)d_ws;

    size_t off = 0;
    auto alloc = [&](size_t n) { float* p = ws + off; off += (n + 63) & ~(size_t)63; return p; };
    float* eW0t = alloc((size_t)INDIM * GDIM);
    float* eR0t = alloc((size_t)HDIM * GDIM);
    float* eW1t = alloc((size_t)HDIM * GDIM);
    float* eR1t = alloc((size_t)HDIM * GDIM);
    float* dW0t = alloc((size_t)INDIM * GDIM);
    float* dR0t = alloc((size_t)HDIM * GDIM);
    float* dW1t = alloc((size_t)HDIM * GDIM);
    float* dR1t = alloc((size_t)HDIM * GDIM);
    float* bte0 = alloc(GDIM);
    float* bte1 = alloc(GDIM);
    float* btd0 = alloc(GDIM);
    float* btd1 = alloc(GDIM);
    float* h0b0 = alloc((size_t)BATCH * HDIM);
    float* h0b1 = alloc((size_t)BATCH * HDIM);
    float* h1b0 = alloc((size_t)BATCH * HDIM);
    float* h1b1 = alloc((size_t)BATCH * HDIM);
    float* c0   = alloc((size_t)BATCH * HDIM);
    float* c1   = alloc((size_t)BATCH * HDIM);
    float* xfb  = alloc((size_t)BATCH * INDIM);
    if (off * sizeof(float) > ws_size) return;  // ws too small: bail (will fail check visibly)

    float* h0b[2] = { h0b0, h0b1 };
    float* h1b[2] = { h1b0, h1b1 };

    // one-time weight/bias reordering (amortized; ~25 MB traffic)
    reorder_w<<<(GDIM * INDIM + 255) / 256, 256, 0, stream>>>(eWih0, eW0t, INDIM);
    reorder_w<<<(GDIM * HDIM) / 256, 256, 0, stream>>>(eWhh0, eR0t, HDIM);
    reorder_w<<<(GDIM * HDIM) / 256, 256, 0, stream>>>(eWih1, eW1t, HDIM);
    reorder_w<<<(GDIM * HDIM) / 256, 256, 0, stream>>>(eWhh1, eR1t, HDIM);
    reorder_w<<<(GDIM * INDIM + 255) / 256, 256, 0, stream>>>(dWih0, dW0t, INDIM);
    reorder_w<<<(GDIM * HDIM) / 256, 256, 0, stream>>>(dWhh0, dR0t, HDIM);
    reorder_w<<<(GDIM * HDIM) / 256, 256, 0, stream>>>(dWih1, dW1t, HDIM);
    reorder_w<<<(GDIM * HDIM) / 256, 256, 0, stream>>>(dWhh1, dR1t, HDIM);
    reorder_b<<<GDIM / 256, 256, 0, stream>>>(eb0, bte0);
    reorder_b<<<GDIM / 256, 256, 0, stream>>>(eb1, bte1);
    reorder_b<<<GDIM / 256, 256, 0, stream>>>(db0, btd0);
    reorder_b<<<GDIM / 256, 256, 0, stream>>>(db1, btd1);

    hipMemsetAsync(h0b[0], 0, (size_t)BATCH * HDIM * 4, stream);
    hipMemsetAsync(h1b[0], 0, (size_t)BATCH * HDIM * 4, stream);
    hipMemsetAsync(c0, 0, (size_t)BATCH * HDIM * 4, stream);
    hipMemsetAsync(c1, 0, (size_t)BATCH * HDIM * 4, stream);
    hipMemsetAsync(xfb, 0, (size_t)BATCH * INDIM * 4, stream);

    dim3 grid(BATCH / BM, HDIM / BNHL);   // (32,16) = 512 blocks = 2/CU
    int p0 = 0, p1 = 0;

    // ---- encoder ----
    for (int t = 0; t < TSTEPS; ++t) {
        lstm_step<<<grid, 256, 0, stream>>>(X + t * INDIM, TSTEPS * INDIM, INDIM, eW0t,
                                            h0b[p0], eR0t, bte0, c0, h0b[p0 ^ 1], c0);
        p0 ^= 1;
        lstm_step<<<grid, 256, 0, stream>>>(h0b[p0], HDIM, HDIM, eW1t,
                                            h1b[p1], eR1t, bte1, c1, h1b[p1 ^ 1], c1);
        p1 ^= 1;
    }
    // ---- decoder (autoregressive, softmax feedback) ----
    for (int t = 0; t < TSTEPS; ++t) {
        lstm_step<<<grid, 256, 0, stream>>>(xfb, INDIM, INDIM, dW0t,
                                            h0b[p0], dR0t, btd0, c0, h0b[p0 ^ 1], c0);
        p0 ^= 1;
        lstm_step<<<grid, 256, 0, stream>>>(h0b[p0], HDIM, HDIM, dW1t,
                                            h1b[p1], dR1t, btd1, c1, h1b[p1 ^ 1], c1);
        p1 ^= 1;
        pred_softmax<<<BATCH / 16, 256, 0, stream>>>(h1b[p1], Wp, bp, out + t * INDIM, xfb);
    }
    (void)in_sizes; (void)n_in; (void)out_size;
}

// Round 2
// 24600.557 us; speedup vs baseline: 1.2819x; 1.2819x over previous
//
#include <hip/hip_runtime.h>
#include <math.h>
#include <stdint.h>

typedef _Float16 f16;
typedef _Float16 f16x8 __attribute__((ext_vector_type(8)));
typedef float f32x4 __attribute__((ext_vector_type(4)));

#define BATCH 1024
#define HD    512
#define TST   100
#define BUFSZ 49152   // 32KB A-tile + 16KB B-tile

// ---------------- setup kernels ----------------
// Weights -> pre-split (hi/lo fp16, x32/x2048 scaling), pre-permuted (row m = hl*4+g),
// pre-arranged in the exact LDS image order (incl. XOR slot swizzle) per (mtile, ktile).
__global__ void split_w(const float* __restrict__ src0, int ksplit,
                        const float* __restrict__ src1, int NKT, f16* __restrict__ out)
{
    int c = blockIdx.x * 256 + threadIdx.x;
    int total = 16 * NKT * 2048;
    if (c >= total) return;
    int u = c & 2047;
    int t2 = c >> 11;          // mt*NKT + kt
    int kt = t2 % NKT;
    int mt = t2 / NKT;
    int line = u >> 4;
    int s = (u & 15) ^ (line & 15);   // content slot at this LDS position
    int plane = s >> 3, o = s & 7;
    int m = mt * 128 + line;
    int row = (m & 3) * HD + (m >> 2);    // original row g*512+hl
    int kb = kt * 64 + o * 8;
    f16 v[8];
    #pragma unroll
    for (int e = 0; e < 8; ++e) {
        int k = kb + e;
        float w = (k < ksplit) ? src0[(size_t)row * ksplit + k]
                               : src1[(size_t)row * HD + (k - ksplit)];
        float w32 = w * 32.0f;
        f16 hi = (f16)w32;
        v[e] = plane ? (f16)((w32 - (float)hi) * 2048.0f) : hi;
    }
    *(f16x8*)(out + (size_t)c * 8) = *(f16x8*)v;
}

__global__ void prep_b4(const float* __restrict__ b, float* __restrict__ bt) {
    int c = blockIdx.x * 256 + threadIdx.x;     // c = hl*4+g
    if (c < 2048) bt[c] = b[(c & 3) * HD + (c >> 2)];
}

__global__ void prep_wih4(const float* __restrict__ W, float* __restrict__ o) {
    int c = blockIdx.x * 256 + threadIdx.x;     // c = hl*16 + g*4 + j
    if (c < 8192) {
        int j = c & 3, g = (c >> 2) & 3, hl = c >> 4;
        o[c] = W[(size_t)(g * HD + hl) * 4 + j];
    }
}

// ---------------- fused LSTM layer-step (MFMA, fp16 split-2, 3-pass) ----------------
// gates^T[2048 x 1024] = Wsplit[2048 x K] @ xcat^T[K x 1024]; K = 512 (NKT=8) or 1024 (NKT=16).
// B source: k<512 -> src1, k>=512 -> src2 (fp16 lines: [hi 512][lo 512]).
// Optional rank-4 input term (4-dim x) added in fp32 epilogue.
template<int NKT, bool RANK4>
__launch_bounds__(256, 1) __global__
void lstm_mfma(const f16* __restrict__ Wst, const f16* __restrict__ src1,
               const f16* __restrict__ src2, const float* __restrict__ wih4,
               const float* __restrict__ xin, int xstride, const float* __restrict__ bt4,
               float* __restrict__ cT, f16* __restrict__ hout)
{
    __shared__ __align__(16) char smem[2 * BUFSZ];
    const int tid = threadIdx.x;
    const int lane = tid & 63;
    const int wv = tid >> 6;            // wave 0..3
    const int wm = wv & 1, wn = wv >> 1;
    const int l15 = lane & 15, j = lane >> 4;

    // bijective XCD-aware mapping: XCD x owns M-tiles {2x,2x+1} (A-slice fetched once per XCD)
    const int bx = blockIdx.x;
    const int xcd = bx & 7, idx = bx >> 3;
    const int mt = (xcd << 1) | (idx & 1);   // 0..15
    const int nt = idx >> 1;                 // 0..15
    const int m0 = mt * 128, n0 = nt * 64;

    // fragment LDS addressing (16B slot XOR swizzle: s' = s ^ (line&15))
    const int q = (j ^ l15) << 4;
    int ALr[4], BLb[2];
    #pragma unroll
    for (int f = 0; f < 4; ++f) ALr[f] = (wm * 64 + f * 16 + l15) * 256;
    #pragma unroll
    for (int fn = 0; fn < 2; ++fn) BLb[fn] = 32768 + (wn * 32 + fn * 16 + l15) * 256;

    float4 ra[8], rb[4];

    auto issue = [&](int kt) {
        const float4* ga = (const float4*)(Wst + ((size_t)mt * NKT + kt) * 2048 * 8);
        #pragma unroll
        for (int i = 0; i < 8; ++i) ra[i] = ga[i * 256 + tid];
        #pragma unroll
        for (int i = 0; i < 4; ++i) {
            int v = i * 256 + tid;
            int line = v >> 4;
            int s = (v & 15) ^ (line & 15);
            int ks = kt * 64 + (s & 7) * 8;
            const f16* sp = src1; int kl = ks;
            if (NKT == 16 && ks >= 512) { sp = src2; kl = ks - 512; }
            rb[i] = *(const float4*)(sp + (size_t)(n0 + line) * 1024 + (s >> 3) * 512 + kl);
        }
    };

    f32x4 accA[4][2] = {};
    f32x4 accB[4][2] = {};

    issue(0);
    for (int kt = 0; kt < NKT; ++kt) {
        char* buf = smem + (kt & 1) * BUFSZ;
        #pragma unroll
        for (int i = 0; i < 8; ++i) *(float4*)(buf + (i * 256 + tid) * 16) = ra[i];
        #pragma unroll
        for (int i = 0; i < 4; ++i) *(float4*)(buf + 32768 + (i * 256 + tid) * 16) = rb[i];
        if (kt + 1 < NKT) issue(kt + 1);    // loads for next tile in flight across compute
        __syncthreads();
        #pragma unroll
        for (int i = 0; i < 2; ++i) {       // two k32 steps per BK=64
            const int off = (i << 6) ^ q;
            f16x8 ah[4], al[4], bh[2], bl[2];
            #pragma unroll
            for (int f = 0; f < 4; ++f) {
                ah[f] = *(const f16x8*)(buf + ALr[f] + off);
                al[f] = *(const f16x8*)(buf + ALr[f] + (off ^ 0x80));
            }
            #pragma unroll
            for (int fn = 0; fn < 2; ++fn) {
                bh[fn] = *(const f16x8*)(buf + BLb[fn] + off);
                bl[fn] = *(const f16x8*)(buf + BLb[fn] + (off ^ 0x80));
            }
            #pragma unroll
            for (int f = 0; f < 4; ++f)
                #pragma unroll
                for (int fn = 0; fn < 2; ++fn) {
                    accA[f][fn] = __builtin_amdgcn_mfma_f32_16x16x32_f16(ah[f], bh[fn], accA[f][fn], 0, 0, 0);
                    accB[f][fn] = __builtin_amdgcn_mfma_f32_16x16x32_f16(al[f], bh[fn], accB[f][fn], 0, 0, 0);
                    accB[f][fn] = __builtin_amdgcn_mfma_f32_16x16x32_f16(ah[f], bl[fn], accB[f][fn], 0, 0, 0);
                }
        }
    }

    // ---------------- epilogue: cell update in registers ----------------
    // D-frag: col(n) = lane&15, row = (lane>>4)*4 + r  ->  regs r=0..3 are gates i,f,g,o of one hl.
    const float sA = 1.0f / 1024.0f;
    const float sB = 1.0f / (1024.0f * 2048.0f);
    uint32_t* htile = (uint32_t*)smem;     // [64][33] u32, disjoint from last-used buffer (odd)
    #pragma unroll
    for (int f = 0; f < 4; ++f) {
        const int hl_loc = wm * 16 + f * 4 + j;
        const int hl = mt * 32 + hl_loc;
        const float4 bv = *(const float4*)(bt4 + hl * 4);
        #pragma unroll
        for (int fn = 0; fn < 2; ++fn) {
            const int n_loc = wn * 32 + fn * 16 + l15;
            const int n = n0 + n_loc;
            float g0 = accA[f][fn][0] * sA + accB[f][fn][0] * sB + bv.x;
            float g1 = accA[f][fn][1] * sA + accB[f][fn][1] * sB + bv.y;
            float g2 = accA[f][fn][2] * sA + accB[f][fn][2] * sB + bv.z;
            float g3 = accA[f][fn][3] * sA + accB[f][fn][3] * sB + bv.w;
            if (RANK4) {
                const float4* wr = (const float4*)(wih4 + hl * 16);
                const float4 x4 = *(const float4*)(xin + (size_t)n * xstride);
                g0 += wr[0].x * x4.x + wr[0].y * x4.y + wr[0].z * x4.z + wr[0].w * x4.w;
                g1 += wr[1].x * x4.x + wr[1].y * x4.y + wr[1].z * x4.z + wr[1].w * x4.w;
                g2 += wr[2].x * x4.x + wr[2].y * x4.y + wr[2].z * x4.z + wr[2].w * x4.w;
                g3 += wr[3].x * x4.x + wr[3].y * x4.y + wr[3].z * x4.z + wr[3].w * x4.w;
            }
            const size_t co = (size_t)hl * 1024 + n;
            const float cold = cT[co];
            const float si = 1.0f / (1.0f + expf(-g0));
            const float sf = 1.0f / (1.0f + expf(-g1));
            const float so = 1.0f / (1.0f + expf(-g3));
            const float cn = sf * cold + si * tanhf(g2);
            const float hn = so * tanhf(cn);
            cT[co] = cn;
            const float h32 = hn * 32.0f;
            const f16 hi = (f16)h32;
            const f16 lo = (f16)((h32 - (float)hi) * 2048.0f);
            uint32_t pk = ((uint32_t)__builtin_bit_cast(uint16_t, lo) << 16)
                        | (uint32_t)__builtin_bit_cast(uint16_t, hi);
            htile[n_loc * 33 + hl_loc] = pk;
        }
    }
    __syncthreads();
    #pragma unroll
    for (int i = 0; i < 8; ++i) {
        int u = i * 256 + tid;              // 0..2047
        int n_loc = u >> 5, hl_loc = u & 31;
        uint32_t pk = htile[n_loc * 33 + hl_loc];
        size_t bi = (size_t)(n0 + n_loc) * 1024 + (mt * 32 + hl_loc);
        hout[bi]       = __builtin_bit_cast(f16, (uint16_t)(pk & 0xffff));
        hout[bi + 512] = __builtin_bit_cast(f16, (uint16_t)(pk >> 16));
    }
}

// ---------------- pred = h1 @ Wp.T + bp ; softmax -> xfb ----------------
__global__ void pred_softmax(const f16* __restrict__ h1, const float* __restrict__ Wp,
                             const float* __restrict__ bp, float* __restrict__ outp,
                             float* __restrict__ xfb)
{
    const int tid = threadIdx.x;
    const int b = blockIdx.x * 16 + (tid >> 4);
    const int l = tid & 15;
    const f16* hr = h1 + (size_t)b * 1024;
    float a0 = 0.f, a1 = 0.f, a2 = 0.f, a3 = 0.f;
    #pragma unroll
    for (int jj = 0; jj < 4; ++jj) {
        int k0 = jj * 128 + l * 8;
        f16x8 hv = *(const f16x8*)(hr + k0);
        f16x8 lv = *(const f16x8*)(hr + 512 + k0);
        float h[8];
        #pragma unroll
        for (int e = 0; e < 8; ++e)
            h[e] = (float)hv[e] * 0.03125f + (float)lv[e] * (1.0f / 65536.0f);
        #pragma unroll
        for (int r = 0; r < 4; ++r) {
            const float4 wa = *(const float4*)(Wp + r * HD + k0);
            const float4 wb = *(const float4*)(Wp + r * HD + k0 + 4);
            float d = h[0] * wa.x + h[1] * wa.y + h[2] * wa.z + h[3] * wa.w
                    + h[4] * wb.x + h[5] * wb.y + h[6] * wb.z + h[7] * wb.w;
            if (r == 0) a0 += d; else if (r == 1) a1 += d; else if (r == 2) a2 += d; else a3 += d;
        }
    }
    #pragma unroll
    for (int off = 8; off > 0; off >>= 1) {
        a0 += __shfl_xor(a0, off, 16);
        a1 += __shfl_xor(a1, off, 16);
        a2 += __shfl_xor(a2, off, 16);
        a3 += __shfl_xor(a3, off, 16);
    }
    if (l == 0) {
        const float4 bv = *(const float4*)bp;
        float v0 = a0 + bv.x, v1 = a1 + bv.y, v2 = a2 + bv.z, v3 = a3 + bv.w;
        float* op = outp + (size_t)b * (TST * 4);
        op[0] = v0; op[1] = v1; op[2] = v2; op[3] = v3;
        float m = fmaxf(fmaxf(v0, v1), fmaxf(v2, v3));
        float e0 = expf(v0 - m), e1 = expf(v1 - m), e2 = expf(v2 - m), e3 = expf(v3 - m);
        float inv = 1.0f / (e0 + e1 + e2 + e3);
        float* xp = xfb + b * 4;
        xp[0] = e0 * inv; xp[1] = e1 * inv; xp[2] = e2 * inv; xp[3] = e3 * inv;
    }
}

// ---------------- host ----------------
extern "C" void kernel_launch(void* const* d_in, const int* in_sizes, int n_in,
                              void* d_out, int out_size, void* d_ws, size_t ws_size,
                              hipStream_t stream)
{
    const float* X     = (const float*)d_in[0];
    const float* eWih0 = (const float*)d_in[2];
    const float* eWhh0 = (const float*)d_in[3];
    const float* eb0   = (const float*)d_in[4];
    const float* eWih1 = (const float*)d_in[5];
    const float* eWhh1 = (const float*)d_in[6];
    const float* eb1   = (const float*)d_in[7];
    const float* dWih0 = (const float*)d_in[8];
    const float* dWhh0 = (const float*)d_in[9];
    const float* db0   = (const float*)d_in[10];
    const float* dWih1 = (const float*)d_in[11];
    const float* dWhh1 = (const float*)d_in[12];
    const float* db1   = (const float*)d_in[13];
    const float* Wp    = (const float*)d_in[14];
    const float* bp    = (const float*)d_in[15];
    float* out = (float*)d_out;

    char* ws = (char*)d_ws;
    size_t off = 0;
    auto alloc = [&](size_t bytes) { char* p = ws + off; off += (bytes + 255) & ~(size_t)255; return p; };
    f16* Wst_e0 = (f16*)alloc((size_t)16 * 8  * 2048 * 16);
    f16* Wst_e1 = (f16*)alloc((size_t)16 * 16 * 2048 * 16);
    f16* Wst_d0 = (f16*)alloc((size_t)16 * 8  * 2048 * 16);
    f16* Wst_d1 = (f16*)alloc((size_t)16 * 16 * 2048 * 16);
    float* wih4_e = (float*)alloc(8192 * 4);
    float* wih4_d = (float*)alloc(8192 * 4);
    float* bt_e0 = (float*)alloc(2048 * 4);
    float* bt_e1 = (float*)alloc(2048 * 4);
    float* bt_d0 = (float*)alloc(2048 * 4);
    float* bt_d1 = (float*)alloc(2048 * 4);
    f16* h0a = (f16*)alloc((size_t)BATCH * 1024 * 2);
    f16* h0b = (f16*)alloc((size_t)BATCH * 1024 * 2);
    f16* h1a = (f16*)alloc((size_t)BATCH * 1024 * 2);
    f16* h1b = (f16*)alloc((size_t)BATCH * 1024 * 2);
    float* c0T = (float*)alloc((size_t)HD * BATCH * 4);
    float* c1T = (float*)alloc((size_t)HD * BATCH * 4);
    float* xfb = (float*)alloc((size_t)BATCH * 4 * 4);
    if (off > ws_size) return;   // workspace too small -> loud failure

    // one-time weight prep
    split_w<<<(16 * 8  * 2048) / 256, 256, 0, stream>>>(nullptr, 0,   eWhh0, 8,  Wst_e0);
    split_w<<<(16 * 16 * 2048) / 256, 256, 0, stream>>>(eWih1, 512, eWhh1, 16, Wst_e1);
    split_w<<<(16 * 8  * 2048) / 256, 256, 0, stream>>>(nullptr, 0,   dWhh0, 8,  Wst_d0);
    split_w<<<(16 * 16 * 2048) / 256, 256, 0, stream>>>(dWih1, 512, dWhh1, 16, Wst_d1);
    prep_wih4<<<32, 256, 0, stream>>>(eWih0, wih4_e);
    prep_wih4<<<32, 256, 0, stream>>>(dWih0, wih4_d);
    prep_b4<<<8, 256, 0, stream>>>(eb0, bt_e0);
    prep_b4<<<8, 256, 0, stream>>>(eb1, bt_e1);
    prep_b4<<<8, 256, 0, stream>>>(db0, bt_d0);
    prep_b4<<<8, 256, 0, stream>>>(db1, bt_d1);

    hipMemsetAsync(h0a, 0, (size_t)BATCH * 1024 * 2, stream);
    hipMemsetAsync(h1a, 0, (size_t)BATCH * 1024 * 2, stream);
    hipMemsetAsync(c0T, 0, (size_t)HD * BATCH * 4, stream);
    hipMemsetAsync(c1T, 0, (size_t)HD * BATCH * 4, stream);
    hipMemsetAsync(xfb, 0, (size_t)BATCH * 4 * 4, stream);

    f16* h0[2] = { h0a, h0b };
    f16* h1[2] = { h1a, h1b };
    int p0 = 0, p1 = 0;

    // ---- encoder ----
    for (int t = 0; t < TST; ++t) {
        lstm_mfma<8, true><<<256, 256, 0, stream>>>(Wst_e0, h0[p0], nullptr, wih4_e,
                                                    X + t * 4, TST * 4, bt_e0, c0T, h0[p0 ^ 1]);
        p0 ^= 1;
        lstm_mfma<16, false><<<256, 256, 0, stream>>>(Wst_e1, h0[p0], h1[p1], nullptr,
                                                      nullptr, 0, bt_e1, c1T, h1[p1 ^ 1]);
        p1 ^= 1;
    }
    // ---- decoder (autoregressive, softmax feedback) ----
    for (int t = 0; t < TST; ++t) {
        lstm_mfma<8, true><<<256, 256, 0, stream>>>(Wst_d0, h0[p0], nullptr, wih4_d,
                                                    xfb, 4, bt_d0, c0T, h0[p0 ^ 1]);
        p0 ^= 1;
        lstm_mfma<16, false><<<256, 256, 0, stream>>>(Wst_d1, h0[p0], h1[p1], nullptr,
                                                      nullptr, 0, bt_d1, c1T, h1[p1 ^ 1]);
        p1 ^= 1;
        pred_softmax<<<BATCH / 16, 256, 0, stream>>>(h1[p1], Wp, bp, out + t * 4, xfb);
    }
    (void)in_sizes; (void)n_in; (void)out_size;
}